// Round 10
// baseline (481.975 us; speedup 1.0000x reference)
//
#include <hip/hip_runtime.h>

// SpatialHRVQTokenizer: 3-level VQ forward.
// Main GEMM: single-term f16 MFMA (hi*hi); rows with approx top-2 gap < RTAU=0.5
// are re-solved in DOUBLE precision vs all 256 codes (argmin independent of fp32
// rounding order -- r8/r9 lesson: fp32 fmaf(xn) rounding luck flips ulp-scale ties).
// Output (flat fp32): idx0[0,32768) idx1[...,163840) idx2[...,294912)
//   loss[294912]  q0[294913..)  q1[12877825..)  q2[63209473..)

typedef _Float16 half8 __attribute__((ext_vector_type(8)));
typedef float f32x16 __attribute__((ext_vector_type(16)));

#define D_MODEL 384
#define NSEG 96
#define NKT 12
#define BM 64
#define RTAU 0.5f

__device__ __forceinline__ float4 ld4(const float* p) { return *(const float4*)p; }

__device__ __forceinline__ half8 cvt8h(const float4& a, const float4& b) {
  half8 h;
  h[0] = (_Float16)a.x; h[1] = (_Float16)a.y; h[2] = (_Float16)a.z; h[3] = (_Float16)a.w;
  h[4] = (_Float16)b.x; h[5] = (_Float16)b.y; h[6] = (_Float16)b.z; h[7] = (_Float16)b.w;
  return h;
}

__device__ __forceinline__ void gload_lds16(const void* g, void* l) {
  __builtin_amdgcn_global_load_lds(
      (const __attribute__((address_space(1))) unsigned int*)g,
      (__attribute__((address_space(3))) unsigned int*)l, 16, 0, 0);
}

// ---------------- code norms + counter zeroing ----------------
__global__ __launch_bounds__(64) void vq_norms(const float* __restrict__ c0,
                                               const float* __restrict__ c1,
                                               const float* __restrict__ c2,
                                               float* __restrict__ en,
                                               int* __restrict__ counts) {
  if (blockIdx.x == 0 && threadIdx.x < 4) counts[threadIdx.x] = 0;
  const int row = blockIdx.x;  // 0..767
  const float* cb = (row < 256) ? c0 : ((row < 512) ? c1 : c2);
  const int n = row & 255;
  const int lane = threadIdx.x;
  const float* r = cb + (size_t)n * D_MODEL;
  float s = 0.f;
  for (int c = lane; c < D_MODEL; c += 64) s = fmaf(r[c], r[c], s);
  for (int m = 1; m < 64; m <<= 1) s += __shfl_xor(s, m, 64);
  if (lane == 0) en[row] = s;
}

// ---------------- precompute f16(hi) codebook, fragment-linear ----------------
__global__ __launch_bounds__(256) void vq_split_cb(const float* __restrict__ c0,
                                                   const float* __restrict__ c1,
                                                   const float* __restrict__ c2,
                                                   half8* __restrict__ bh) {
  const int t = blockIdx.x * 256 + threadIdx.x;    // 0..36863
  const int lvl = t / 12288;
  const int rem = t - lvl * 12288;
  const int kt = rem >> 10;
  const int f = (rem >> 6) & 15;
  const int lane = rem & 63;
  const int code = (f >> 1) * 32 + (lane & 31);
  const int k0 = kt * 32 + (f & 1) * 16 + (lane >> 5) * 8;
  const float* cb = (lvl == 0) ? c0 : ((lvl == 1) ? c1 : c2);
  const float4 a = ld4(cb + code * D_MODEL + k0);
  const float4 b = ld4(cb + code * D_MODEL + k0 + 4);
  bh[t] = cvt8h(a, b);
}

// ---------------- fused main VQ kernel, all 3 levels (r9 structure) ----------------
__global__ __launch_bounds__(256, 3) void vq_mfma_all(
    const float* __restrict__ l0, const float* __restrict__ l1,
    const float* __restrict__ l2, const float* __restrict__ c0,
    const float* __restrict__ c1, const float* __restrict__ c2,
    const float* __restrict__ en_all,
    const half8* __restrict__ bh_pre,
    float* __restrict__ out, float* __restrict__ dmin_all,
    float* __restrict__ xn_all,
    int* __restrict__ list0, int* __restrict__ list1, int* __restrict__ list2,
    int* __restrict__ counts) {
  __shared__ __align__(16) unsigned char smem[40960];
  float*  scanbuf = (float*)smem;           //     0..32768  [32][256]
  float4* red     = (float4*)(smem + 32768);// 32768..36864  [32][8]
  float*  en_s    = (float*)(smem + 36864); // 36864..37888  [256]
  float4* rowres  = (float4*)(smem + 37888);// 37888..38912  [64]
  float*  xns     = (float*)(smem + 38912); // 38912..39168  [64]
  int*    idxs    = (int*)(smem + 39168);   // 39168..39424  [64]

  const int swz = (blockIdx.x & 7) * 576 + (blockIdx.x >> 3);
  int lvl, blk;
  if (swz < 512)       { lvl = 0; blk = swz; }
  else if (swz < 2560) { lvl = 1; blk = swz - 512; }
  else                 { lvl = 2; blk = swz - 2560; }
  const float* x  = (lvl == 0) ? l0 : ((lvl == 1) ? l1 : l2);
  const float* cb = (lvl == 0) ? c0 : ((lvl == 1) ? c1 : c2);
  const float* en = en_all + lvl * 256;
  const half8* bh = bh_pre + lvl * 12288;
  const long ioff = (lvl == 0) ? 0 : ((lvl == 1) ? 32768 : 163840);
  float* out_idx = out + ioff;
  float* out_q   = out + ((lvl == 0) ? 294913L : ((lvl == 1) ? 12877825L : 63209473L));
  float* dmin_lvl = dmin_all + ioff;
  float* xn_lvl   = xn_all + ioff;
  int* list = (lvl == 0) ? list0 : ((lvl == 1) ? list1 : list2);
  int* cnt  = counts + lvl;

  const int tid = threadIdx.x;
  const int lane = tid & 63;
  const int w = tid >> 6, wm = w >> 1, wn = w & 1;
  const int c31 = lane & 31, h = lane >> 5;
  const long m0 = (long)blk * BM;

  const float* ap = x + (m0 + wm * 32 + c31) * (long)D_MODEL + h * 8;

  f32x16 acc[4];
#pragma unroll
  for (int n = 0; n < 4; ++n)
#pragma unroll
    for (int i = 0; i < 16; ++i) acc[n][i] = 0.f;

  float xn_part = 0.f;

  float4 ra0 = ld4(ap + 0), ra1 = ld4(ap + 4), ra2 = ld4(ap + 16), ra3 = ld4(ap + 20);
#pragma unroll
  for (int r = 0; r < 4; ++r) {
    const int f = r * 4 + w;
    gload_lds16(bh + (size_t)(f * 64 + lane), (void*)(smem + f * 1024));
  }
  xn_part = fmaf(ra0.x, ra0.x, xn_part); xn_part = fmaf(ra0.y, ra0.y, xn_part);
  xn_part = fmaf(ra0.z, ra0.z, xn_part); xn_part = fmaf(ra0.w, ra0.w, xn_part);
  xn_part = fmaf(ra1.x, ra1.x, xn_part); xn_part = fmaf(ra1.y, ra1.y, xn_part);
  xn_part = fmaf(ra1.z, ra1.z, xn_part); xn_part = fmaf(ra1.w, ra1.w, xn_part);
  xn_part = fmaf(ra2.x, ra2.x, xn_part); xn_part = fmaf(ra2.y, ra2.y, xn_part);
  xn_part = fmaf(ra2.z, ra2.z, xn_part); xn_part = fmaf(ra2.w, ra2.w, xn_part);
  xn_part = fmaf(ra3.x, ra3.x, xn_part); xn_part = fmaf(ra3.y, ra3.y, xn_part);
  xn_part = fmaf(ra3.z, ra3.z, xn_part); xn_part = fmaf(ra3.w, ra3.w, xn_part);
  half8 ahc0 = cvt8h(ra0, ra1);
  half8 ahc1 = cvt8h(ra2, ra3);
  __syncthreads();   // X(0)

#pragma unroll
  for (int kt = 0; kt < NKT; ++kt) {
    const int cur = kt & 1;
    const int nxt = cur ^ 1;
    float4 rb0, rb1, rb2, rb3;
    if (kt + 1 < NKT) {
#pragma unroll
      for (int r = 0; r < 4; ++r) {
        const int f = r * 4 + w;
        gload_lds16(bh + (size_t)(kt + 1) * 1024 + (size_t)(f * 64 + lane),
                    (void*)(smem + nxt * 16384 + f * 1024));
      }
      const int ko = (kt + 1) * 32;
      rb0 = ld4(ap + ko); rb1 = ld4(ap + ko + 4);
      rb2 = ld4(ap + ko + 16); rb3 = ld4(ap + ko + 20);
    }
    {
      const half8* Bh = (const half8*)(smem + cur * 16384);
#pragma unroll
      for (int n = 0; n < 4; ++n) {
        const int nt = wn * 4 + n;
        half8 b0 = Bh[(nt * 2 + 0) * 64 + lane];
        half8 b1 = Bh[(nt * 2 + 1) * 64 + lane];
        acc[n] = __builtin_amdgcn_mfma_f32_32x32x16_f16(ahc0, b0, acc[n], 0, 0, 0);
        acc[n] = __builtin_amdgcn_mfma_f32_32x32x16_f16(ahc1, b1, acc[n], 0, 0, 0);
      }
    }
    if (kt + 1 < NKT) {
      xn_part = fmaf(rb0.x, rb0.x, xn_part); xn_part = fmaf(rb0.y, rb0.y, xn_part);
      xn_part = fmaf(rb0.z, rb0.z, xn_part); xn_part = fmaf(rb0.w, rb0.w, xn_part);
      xn_part = fmaf(rb1.x, rb1.x, xn_part); xn_part = fmaf(rb1.y, rb1.y, xn_part);
      xn_part = fmaf(rb1.z, rb1.z, xn_part); xn_part = fmaf(rb1.w, rb1.w, xn_part);
      xn_part = fmaf(rb2.x, rb2.x, xn_part); xn_part = fmaf(rb2.y, rb2.y, xn_part);
      xn_part = fmaf(rb2.z, rb2.z, xn_part); xn_part = fmaf(rb2.w, rb2.w, xn_part);
      xn_part = fmaf(rb3.x, rb3.x, xn_part); xn_part = fmaf(rb3.y, rb3.y, xn_part);
      xn_part = fmaf(rb3.z, rb3.z, xn_part); xn_part = fmaf(rb3.w, rb3.w, xn_part);
      ahc0 = cvt8h(rb0, rb1);
      ahc1 = cvt8h(rb2, rb3);
      __syncthreads();   // X(kt+1)
    }
  }

  {
    const float xr = xn_part + __shfl_xor(xn_part, 32, 64);
    if (wn == 0 && lane < 32) xns[wm * 32 + lane] = xr;
  }
  en_s[tid] = en[tid];

#pragma unroll 1
  for (int b = 0; b < 2; ++b) {
    __syncthreads();
    if (wm == b) {
#pragma unroll
      for (int n = 0; n < 4; ++n) {
        const int colbase = wn * 128 + n * 32 + c31;
#pragma unroll
        for (int rr = 0; rr < 16; ++rr) {
          const int row_b = (rr & 3) + ((rr >> 2) << 3) + (h << 2);
          const int p = colbase ^ ((row_b & 3) << 3);
          scanbuf[row_b * 256 + p] = fmaf(-2.f, acc[n][rr], en_s[colbase]);
        }
      }
    }
    __syncthreads();
    {
      const int srow = tid >> 3, chunk = tid & 7;
      float b1 = 1e30f, b2 = 1e30f; int i1 = 0, i2 = 0;
#pragma unroll
      for (int u = 0; u < 32; ++u) {
        const int col = chunk + u * 8;
        const float d = scanbuf[srow * 256 + (col ^ ((srow & 3) << 3))];
        if (d < b1) { b2 = b1; i2 = i1; b1 = d; i1 = col; }
        else if (d < b2) { b2 = d; i2 = col; }
      }
      red[srow * 8 + chunk] = make_float4(b1, __int_as_float(i1), b2, __int_as_float(i2));
    }
    __syncthreads();
    if (tid < 32) {
      float4 q = red[tid * 8 + 0];
      float fb1 = q.x, fb2 = q.z;
      int fi1 = __float_as_int(q.y), fi2 = __float_as_int(q.w);
#pragma unroll
      for (int c = 1; c < 8; ++c) {
        q = red[tid * 8 + c];
        const float c1 = q.x, c2 = q.z;
        const int j1 = __float_as_int(q.y), j2 = __float_as_int(q.w);
        if (c1 < fb1 || (c1 == fb1 && j1 < fi1)) {
          if (fb1 < c2 || (fb1 == c2 && fi1 < j2)) { fb2 = fb1; fi2 = fi1; }
          else { fb2 = c2; fi2 = j2; }
          fb1 = c1; fi1 = j1;
        } else if (c1 < fb2 || (c1 == fb2 && j1 < fi2)) { fb2 = c1; fi2 = j1; }
      }
      rowres[b * 32 + tid] = make_float4(fb1, __int_as_float(fi1), fb2, __int_as_float(fi2));
    }
  }
  __syncthreads();

  if (tid < BM) {
    const int m = tid;
    const float4 qv = rowres[m];
    const float fb1 = qv.x, fb2 = qv.z;
    const int fi1 = __float_as_int(qv.y);
    const float xn = xns[m];
    idxs[m] = fi1;
    out_idx[m0 + m] = (float)fi1;
    dmin_lvl[m0 + m] = xn + fb1;
    xn_lvl[m0 + m] = xn;
    const bool flg = (fb2 - fb1 < RTAU);
    const unsigned long long mask = __ballot(flg);
    const int nf = __popcll(mask);
    int base = 0;
    if (tid == 0 && nf) base = atomicAdd(cnt, nf);
    base = __shfl(base, 0, 64);
    if (flg) {
      const int pos = __popcll(mask & ((1ull << tid) - 1ull));
      list[base + pos] = (int)(m0 + m);
    }
  }
  __syncthreads();

  float* qb = out_q + m0 * (long)D_MODEL;
  for (int g = tid; g < BM * NSEG; g += 256) {
    const int m = g / NSEG;
    const int seg = g - m * NSEG;
    *(float4*)(qb + m * (long)D_MODEL + seg * 4) = ld4(cb + (long)idxs[m] * D_MODEL + seg * 4);
  }
}

// ---------------- fused DOUBLE-precision rescue, all 3 levels ----------------
// Self-contained: d~_c = sum(c^2) - 2*sum(c*x) in fp64 (argmin invariant to xn).
// True argmin at ~1e-12 resolution -> matches numpy whenever numpy's own fp32
// pipeline resolves the true order.
__global__ __launch_bounds__(256) void vq_rescue_all(
    const float* __restrict__ l0, const float* __restrict__ l1,
    const float* __restrict__ l2, const float* __restrict__ c0,
    const float* __restrict__ c1, const float* __restrict__ c2,
    const float* __restrict__ en_all,
    const int* __restrict__ list0, const int* __restrict__ list1,
    const int* __restrict__ list2, const int* __restrict__ counts,
    float* __restrict__ out, float* __restrict__ dmin_all,
    const float* __restrict__ xn_all) {
  __shared__ float xs[8][D_MODEL];     // 12 KB
  __shared__ double dall[8][256];      // 16 KB
  __shared__ int rows_s[8];
  __shared__ float xns_s[8];
  __shared__ int best_s[8];

  const int lvl = blockIdx.x >> 7;          // 128 blocks per level
  const int sb  = blockIdx.x & 127;
  const float* x  = (lvl == 0) ? l0 : ((lvl == 1) ? l1 : l2);
  const float* cb = (lvl == 0) ? c0 : ((lvl == 1) ? c1 : c2);
  const int* list = (lvl == 0) ? list0 : ((lvl == 1) ? list1 : list2);
  const long ioff = (lvl == 0) ? 0 : ((lvl == 1) ? 32768 : 163840);
  float* out_idx = out + ioff;
  float* out_q   = out + ((lvl == 0) ? 294913L : ((lvl == 1) ? 12877825L : 63209473L));
  float* dmin_lvl = dmin_all + ioff;
  const float* xn_lvl = xn_all + ioff;

  const int tid = threadIdx.x;              // = code index
  const int count = counts[lvl];
  const int nch = (count + 7) >> 3;
  const int w = tid >> 6, lane = tid & 63;
  const float* crow = cb + (long)tid * D_MODEL;

  for (int c = sb; c < nch; c += 128) {
    const int base = c << 3;
    const int R = min(8, count - base);
    if (tid < 8) {
      const int j = min(tid, R - 1);
      const int r = list[base + j];
      rows_s[tid] = r;
      xns_s[tid] = xn_lvl[r];
    }
    __syncthreads();
#pragma unroll
    for (int r = 0; r < 8; ++r)
      if (tid < NSEG) *(float4*)&xs[r][tid * 4] = ld4(x + (long)rows_s[r] * D_MODEL + tid * 4);
    __syncthreads();

    // fp64 dots: thread = code; 8 rows share the code stream
    double en_d = 0.0;
    double dot[8] = {0.0, 0.0, 0.0, 0.0, 0.0, 0.0, 0.0, 0.0};
    for (int k = 0; k < D_MODEL; ++k) {
      const double cd = (double)crow[k];
      en_d = fma(cd, cd, en_d);
#pragma unroll
      for (int r = 0; r < 8; ++r)
        dot[r] = fma(cd, (double)xs[r][k], dot[r]);
    }
#pragma unroll
    for (int r = 0; r < 8; ++r)
      dall[r][tid] = fma(-2.0, dot[r], en_d);
    __syncthreads();

#pragma unroll
    for (int rr = 0; rr < 2; ++rr) {
      const int r = w + rr * 4;
      if (r < R) {
        double best = dall[r][lane]; int bidx = lane;
#pragma unroll
        for (int u = 1; u < 4; ++u) {
          const int code = lane + u * 64;     // ascending per thread
          const double d = dall[r][code];
          if (d < best) { best = d; bidx = code; }
        }
        for (int mm = 1; mm < 64; mm <<= 1) {
          const double ov = __shfl_xor(best, mm, 64);
          const int oi = __shfl_xor(bidx, mm, 64);
          if (ov < best || (ov == best && oi < bidx)) { best = ov; bidx = oi; }
        }
        if (lane == 0) {
          const int row = rows_s[r];
          out_idx[row] = (float)bidx;
          dmin_lvl[row] = xns_s[r] + (float)best;
          best_s[r] = bidx;
        }
      }
    }
    __syncthreads();
#pragma unroll
    for (int r = 0; r < 8; ++r)
      if (r < R && tid < NSEG)
        *(float4*)(out_q + (long)rows_s[r] * D_MODEL + tid * 4) =
            ld4(cb + (long)best_s[r] * D_MODEL + tid * 4);
    __syncthreads();
  }
}

// ---------------- deterministic loss reduce (after rescue) ----------------
__global__ __launch_bounds__(256) void loss_stage1(const float* __restrict__ dmin,
                                                   double* __restrict__ lp) {
  const int b = blockIdx.x;           // 576 blocks x 512 rows
  const int tid = threadIdx.x;
  const long r0 = (long)b * 512;
  __shared__ double sh[256];
  sh[tid] = (double)dmin[r0 + tid] + (double)dmin[r0 + 256 + tid];
  __syncthreads();
  for (int st = 128; st > 0; st >>= 1) {
    if (tid < st) sh[tid] += sh[tid + st];
    __syncthreads();
  }
  if (tid == 0) {
    double scale;
    if (b < 64)       scale = 0.05 / (32768.0 * 384.0);
    else if (b < 320) scale = 0.25 / (131072.0 * 384.0);
    else              scale = 0.60 / (131072.0 * 384.0);
    lp[b] = sh[0] * scale;
  }
}

__global__ __launch_bounds__(256) void loss_stage2(const double* __restrict__ lp,
                                                   float* __restrict__ out_loss) {
  const int tid = threadIdx.x;
  __shared__ double sh[256];
  sh[tid] = lp[tid] + lp[tid + 256] + ((tid < 64) ? lp[tid + 512] : 0.0);
  __syncthreads();
  for (int st = 128; st > 0; st >>= 1) {
    if (tid < st) sh[tid] += sh[tid + st];
    __syncthreads();
  }
  if (tid == 0) out_loss[0] = (float)sh[0];
}

extern "C" void kernel_launch(void* const* d_in, const int* in_sizes, int n_in,
                              void* d_out, int out_size, void* d_ws, size_t ws_size,
                              hipStream_t stream) {
  const float* l0 = (const float*)d_in[0];
  const float* l1 = (const float*)d_in[1];
  const float* l2 = (const float*)d_in[2];
  const float* c0 = (const float*)d_in[3];
  const float* c1 = (const float*)d_in[4];
  const float* c2 = (const float*)d_in[5];
  float* out = (float*)d_out;

  float* wsf = (float*)d_ws;
  int*   counts   = (int*)wsf;               // 4 ints
  float* en       = wsf + 4;                 // 768
  float* dmin_all = wsf + 772;               // 294912
  float* xn_all   = wsf + 295684;            // 294912
  int*   list0    = (int*)(wsf + 590596);    // cap 32768 (= all rows)
  int*   list1    = (int*)(wsf + 623364);    // cap 131072
  int*   list2    = (int*)(wsf + 754436);    // cap 131072
  double* lp      = (double*)(wsf + 885508); // 576 doubles
  half8* bh_pre   = (half8*)(wsf + 886660);  // 36864 half8 (16B-aligned)

  vq_norms<<<768, 64, 0, stream>>>(c0, c1, c2, en, counts);
  vq_split_cb<<<144, 256, 0, stream>>>(c0, c1, c2, bh_pre);

  vq_mfma_all<<<4608, 256, 0, stream>>>(l0, l1, l2, c0, c1, c2, en,
                                        bh_pre, out,
                                        dmin_all, xn_all,
                                        list0, list1, list2, counts);

  vq_rescue_all<<<384, 256, 0, stream>>>(l0, l1, l2, c0, c1, c2, en,
                                         list0, list1, list2, counts,
                                         out, dmin_all, xn_all);

  loss_stage1<<<576, 256, 0, stream>>>(dmin_all, lp);
  loss_stage2<<<1, 256, 0, stream>>>(lp, out + 294912);
}